// Round 2
// baseline (3155.771 us; speedup 1.0000x reference)
//
#include <hip/hip_runtime.h>

// Problem constants (Go 19x19, B=256, history_factor=10)
#define BB 256
#define HH 19
#define WW 19
#define HW 361            // H*W
#define MAXM 3610         // MAX_MOVES

constexpr unsigned PERB = (unsigned)MAXM * (unsigned)HW;   // 1,303,210 elems per batch
constexpr unsigned TOT  = (unsigned)BB * PERB;             // 333,621,760
constexpr unsigned N4   = TOT / 4u;                        // 83,405,440 vec4s
constexpr unsigned N16  = N4 / 4u;                         // 20,851,360 threads (exact)
// Output layout (floats, concatenated in reference return order)
constexpr unsigned OFF_BOARD = 0;                          // B*HW
constexpr unsigned OFF_HIST  = (unsigned)BB * HW;          // 92,416 (16B aligned)
constexpr unsigned OFF_KO    = OFF_HIST + TOT;             // B*2
constexpr unsigned OFF_PASS  = OFF_KO + 2u * BB;           // B
constexpr unsigned OFF_MV    = OFF_PASS + (unsigned)BB;    // B
constexpr unsigned OFF_PL    = OFF_MV + (unsigned)BB;      // B

typedef int   vi4 __attribute__((ext_vector_type(4)));
typedef float vf4 __attribute__((ext_vector_type(4)));

__device__ __forceinline__ float state_of(float v) {
  // where(v==0, 0, where(v==1, 1, -1))
  return (v == 0.0f) ? 0.0f : ((v == 1.0f) ? 1.0f : -1.0f);
}

// Bulk history copy int32 -> float32, with row mv_c replaced by board_state.
// 64 B per thread: 4 independent dwordx4 loads + 4 dwordx4 stores, nontemporal.
__global__ void __launch_bounds__(256) hist_kernel(
    const int* __restrict__ hist, const float* __restrict__ board,
    const int* __restrict__ move_count, float* __restrict__ out)
{
  unsigned t = blockIdx.x * 256u + threadIdx.x;
  if (t >= N16) return;
  unsigned i4 = t * 4u;                 // first vec4 index
  unsigned e  = t * 16u;                // first element index
  unsigned b  = e / PERB;               // constant divisor -> magic mul
  unsigned j  = e - b * PERB;
  const vi4* __restrict__ src = reinterpret_cast<const vi4*>(hist) + i4;
  vf4* __restrict__ dst = reinterpret_cast<vf4*>(out + OFF_HIST) + i4;

  if (j + 15u < PERB) {
    // whole 16-element span inside batch b
    int mv = move_count[b];
    bool valid = (mv < MAXM);
    int mvc = mv < 0 ? 0 : (mv >= MAXM ? MAXM - 1 : mv);
    unsigned start = (unsigned)mvc * (unsigned)HW;
    bool overlap = valid && (j < start + (unsigned)HW) && (j + 16u > start);
    if (!overlap) {
      // pure convert-copy (99.97% of threads)
#pragma unroll
      for (int k = 0; k < 4; ++k) {
        vi4 h = __builtin_nontemporal_load(src + k);
        __builtin_nontemporal_store(__builtin_convertvector(h, vf4), dst + k);
      }
    } else {
      const float* brd = board + (size_t)b * HW;
#pragma unroll
      for (int k = 0; k < 4; ++k) {
        vi4 h = src[k];
        vf4 o;
        unsigned jj = j + (unsigned)(k * 4);
        unsigned d;
        d = jj + 0u - start; o.x = (d < (unsigned)HW) ? state_of(brd[d]) : (float)h.x;
        d = jj + 1u - start; o.y = (d < (unsigned)HW) ? state_of(brd[d]) : (float)h.y;
        d = jj + 2u - start; o.z = (d < (unsigned)HW) ? state_of(brd[d]) : (float)h.z;
        d = jj + 3u - start; o.w = (d < (unsigned)HW) ? state_of(brd[d]) : (float)h.w;
        dst[k] = o;
      }
    }
  } else {
    // batch-boundary span (per-batch size % 16 != 0): per-element, rare
#pragma unroll
    for (int k = 0; k < 4; ++k) {
      vi4 h = src[k];
      float vals[4];
      int hv[4] = {h.x, h.y, h.z, h.w};
#pragma unroll
      for (int q = 0; q < 4; ++q) {
        unsigned ee = e + (unsigned)(k * 4 + q);
        unsigned bb2 = ee / PERB;
        unsigned jj = ee - bb2 * PERB;
        int mv = move_count[bb2];
        int mvc = mv < 0 ? 0 : (mv >= MAXM ? MAXM - 1 : mv);
        unsigned start = (unsigned)mvc * (unsigned)HW;
        bool valid = (mv < MAXM);
        unsigned d = jj - start;
        vals[q] = (valid && d < (unsigned)HW) ? state_of(board[(size_t)bb2 * HW + d])
                                              : (float)hv[q];
      }
      vf4 o; o.x = vals[0]; o.y = vals[1]; o.z = vals[2]; o.w = vals[3];
      dst[k] = o;
    }
  }
}

// Per-batch board update, capture, ko, scalars. One block per batch.
__global__ void __launch_bounds__(128) small_kernel(
    const float* __restrict__ board, const int* __restrict__ cur,
    const int* __restrict__ ko_pts, const int* __restrict__ pass_cnt,
    const int* __restrict__ mvcnt, const int* __restrict__ positions,
    const int* __restrict__ roots, const int* __restrict__ colour,
    const int* __restrict__ cap_groups, const int* __restrict__ cap_sizes,
    const int* __restrict__ total_caps, float* __restrict__ out)
{
  int b = blockIdx.x;
  int t = threadIdx.x;

  int p0 = positions[2 * b], p1 = positions[2 * b + 1];
  bool is_pass = (p0 < 0) || (p1 < 0);
  bool play = !is_pass;
  int row = p0 < 0 ? 0 : (p0 > HH - 1 ? HH - 1 : p0);
  int col = p1 < 0 ? 0 : (p1 > WW - 1 ? WW - 1 : p1);
  int fp = row * WW + col;
  int cp = cur[b];
  int opp = 1 - cp;
  int cgbase = (b * HW + fp) * 4;
  int nr0 = cap_groups[cgbase + 0];
  int nr1 = cap_groups[cgbase + 1];
  int nr2 = cap_groups[cgbase + 2];
  int nr3 = cap_groups[cgbase + 3];

  for (int p = t; p < HW; p += blockDim.x) {
    float v = board[b * HW + p];
    float placed = (play && p == fp) ? (float)cp : v;
    int r = roots[b * HW + p];
    bool eq = (nr0 >= 0 && r == nr0) || (nr1 >= 0 && r == nr1) ||
              (nr2 >= 0 && r == nr2) || (nr3 >= 0 && r == nr3);
    bool cap = eq && (colour[b * HW + p] == opp) && play;
    out[OFF_BOARD + b * HW + p] = cap ? -1.0f : placed;
  }

  if (t == 0) {
    // ko from single-stone capture
    int tc = total_caps[b * HW + fp];
    bool single_cap = (tc == 1) && play;
    int s0 = cap_sizes[cgbase + 0];
    int s1 = cap_sizes[cgbase + 1];
    int s2 = cap_sizes[cgbase + 2];
    int s3 = cap_sizes[cgbase + 3];
    // argmax of (sizes==1): first index where true, else 0
    int dir = (s0 == 1) ? 0 : ((s1 == 1) ? 1 : ((s2 == 1) ? 2 : ((s3 == 1) ? 3 : 0)));
    const int offs[4] = {-WW, WW, -1, 1};
    int nbr = fp + offs[dir];
    // Python floor division / mod (nbr can be negative)
    int rko = (nbr >= 0) ? (nbr / WW) : -(((-nbr) + WW - 1) / WW);
    int cko = nbr - rko * WW;

    int okr, okc;
    if (is_pass) { okr = ko_pts[2 * b]; okc = ko_pts[2 * b + 1]; }
    else if (single_cap) { okr = rko; okc = cko; }
    else { okr = -1; okc = -1; }
    out[OFF_KO + 2 * b + 0] = (float)okr;
    out[OFF_KO + 2 * b + 1] = (float)okc;
    out[OFF_PASS + b] = (float)(is_pass ? pass_cnt[b] + 1 : 0);
    out[OFF_MV + b]   = (float)(mvcnt[b] + 1);
    out[OFF_PL + b]   = (float)(cp ^ 1);
  }
}

extern "C" void kernel_launch(void* const* d_in, const int* in_sizes, int n_in,
                              void* d_out, int out_size, void* d_ws, size_t ws_size,
                              hipStream_t stream) {
  const float* board      = (const float*)d_in[0];
  const int*   cur        = (const int*)d_in[1];
  const int*   ko_pts     = (const int*)d_in[2];
  const int*   pass_cnt   = (const int*)d_in[3];
  const int*   hist       = (const int*)d_in[4];
  const int*   mvcnt      = (const int*)d_in[5];
  const int*   positions  = (const int*)d_in[6];
  const int*   roots      = (const int*)d_in[7];
  const int*   colour     = (const int*)d_in[8];
  const int*   cap_groups = (const int*)d_in[9];
  const int*   cap_sizes  = (const int*)d_in[10];
  const int*   total_caps = (const int*)d_in[11];
  float* out = (float*)d_out;

  unsigned blocks = (N16 + 255u) / 256u;
  hipLaunchKernelGGL(hist_kernel, dim3(blocks), dim3(256), 0, stream,
                     hist, board, mvcnt, out);
  hipLaunchKernelGGL(small_kernel, dim3(BB), dim3(128), 0, stream,
                     board, cur, ko_pts, pass_cnt, mvcnt, positions, roots,
                     colour, cap_groups, cap_sizes, total_caps, out);
}

// Round 3
// 2112.331 us; speedup vs baseline: 1.4940x; 1.4940x over previous
//
#include <hip/hip_runtime.h>

// Problem constants (Go 19x19, B=256, history_factor=10)
#define BB 256
#define HH 19
#define WW 19
#define HW 361            // H*W
#define MAXM 3610         // MAX_MOVES

constexpr unsigned PERB = (unsigned)MAXM * (unsigned)HW;   // 1,303,210 elems per batch
constexpr unsigned TOT  = (unsigned)BB * PERB;             // 333,621,760
constexpr unsigned N4   = TOT / 4u;                        // 83,405,440 vec4s
// Output layout (floats, concatenated in reference return order)
constexpr unsigned OFF_BOARD = 0;                          // B*HW
constexpr unsigned OFF_HIST  = (unsigned)BB * HW;          // 92,416 (16B aligned)
constexpr unsigned OFF_KO    = OFF_HIST + TOT;             // B*2
constexpr unsigned OFF_PASS  = OFF_KO + 2u * BB;           // B
constexpr unsigned OFF_MV    = OFF_PASS + (unsigned)BB;    // B
constexpr unsigned OFF_PL    = OFF_MV + (unsigned)BB;      // B

constexpr unsigned V4_PER_BLOCK = 1024u;                   // 4 vec4s per thread, block-strided
constexpr unsigned HIST_BLOCKS = (N4 + V4_PER_BLOCK - 1u) / V4_PER_BLOCK; // 81451

typedef int   vi4 __attribute__((ext_vector_type(4)));
typedef float vf4 __attribute__((ext_vector_type(4)));

__device__ __forceinline__ float state_of(float v) {
  // where(v==0, 0, where(v==1, 1, -1))
  return (v == 0.0f) ? 0.0f : ((v == 1.0f) ? 1.0f : -1.0f);
}

// Bulk history copy int32 -> float32, with row mv_c replaced by board_state.
// Each thread: 4 vec4s, block-strided so every instruction is a contiguous
// 1 KB wave access (lane i at byte 16*i). Nontemporal stores only.
__global__ void __launch_bounds__(256) hist_kernel(
    const int* __restrict__ hist, const float* __restrict__ board,
    const int* __restrict__ move_count, float* __restrict__ out)
{
  unsigned base = blockIdx.x * V4_PER_BLOCK + threadIdx.x;
  const vi4* __restrict__ src = reinterpret_cast<const vi4*>(hist);
  vf4* __restrict__ dst = reinterpret_cast<vf4*>(out + OFF_HIST);

  // Issue all 4 loads first (independent -> 4 in flight per thread)
  vi4 h[4];
  unsigned i4s[4];
  bool act[4];
#pragma unroll
  for (int k = 0; k < 4; ++k) {
    i4s[k] = base + (unsigned)k * 256u;
    act[k] = i4s[k] < N4;
    if (act[k]) h[k] = src[i4s[k]];
  }

#pragma unroll
  for (int k = 0; k < 4; ++k) {
    if (!act[k]) continue;
    unsigned i4 = i4s[k];
    unsigned e  = i4 * 4u;
    unsigned b  = e / PERB;              // constant divisor -> magic mul
    unsigned j  = e - b * PERB;
    int mv = move_count[b];              // 256 distinct values, L1/L2-hot
    bool valid = (mv < MAXM);
    int mvc = mv < 0 ? 0 : (mv >= MAXM ? MAXM - 1 : mv);
    unsigned start = (unsigned)mvc * (unsigned)HW;
    bool in_batch = (j + 3u < PERB);
    bool overlap = valid && (j < start + (unsigned)HW) && (j + 4u > start);
    vf4 o;
    if (in_batch && !overlap) {
      // pure convert-copy (~99.99% of vec4s)
      o = __builtin_convertvector(h[k], vf4);
    } else if (in_batch) {
      // overlaps the written row
      const float* brd = board + (size_t)b * HW;
      unsigned d;
      d = j + 0u - start; o.x = (d < (unsigned)HW) ? state_of(brd[d]) : (float)h[k].x;
      d = j + 1u - start; o.y = (d < (unsigned)HW) ? state_of(brd[d]) : (float)h[k].y;
      d = j + 2u - start; o.z = (d < (unsigned)HW) ? state_of(brd[d]) : (float)h[k].z;
      d = j + 3u - start; o.w = (d < (unsigned)HW) ? state_of(brd[d]) : (float)h[k].w;
    } else {
      // batch-boundary vec4 (per-batch size % 4 == 2): per-element, rare
      float vals[4];
      int hv[4] = {h[k].x, h[k].y, h[k].z, h[k].w};
#pragma unroll
      for (int q = 0; q < 4; ++q) {
        unsigned ee = e + (unsigned)q;
        unsigned bb2 = ee / PERB;
        unsigned jj = ee - bb2 * PERB;
        int mv2 = move_count[bb2];
        int mvc2 = mv2 < 0 ? 0 : (mv2 >= MAXM ? MAXM - 1 : mv2);
        unsigned st2 = (unsigned)mvc2 * (unsigned)HW;
        bool val2 = (mv2 < MAXM);
        unsigned d = jj - st2;
        vals[q] = (val2 && d < (unsigned)HW) ? state_of(board[(size_t)bb2 * HW + d])
                                             : (float)hv[q];
      }
      o.x = vals[0]; o.y = vals[1]; o.z = vals[2]; o.w = vals[3];
    }
    __builtin_nontemporal_store(o, dst + i4);
  }
}

// Per-batch board update, capture, ko, scalars. One block per batch.
__global__ void __launch_bounds__(128) small_kernel(
    const float* __restrict__ board, const int* __restrict__ cur,
    const int* __restrict__ ko_pts, const int* __restrict__ pass_cnt,
    const int* __restrict__ mvcnt, const int* __restrict__ positions,
    const int* __restrict__ roots, const int* __restrict__ colour,
    const int* __restrict__ cap_groups, const int* __restrict__ cap_sizes,
    const int* __restrict__ total_caps, float* __restrict__ out)
{
  int b = blockIdx.x;
  int t = threadIdx.x;

  int p0 = positions[2 * b], p1 = positions[2 * b + 1];
  bool is_pass = (p0 < 0) || (p1 < 0);
  bool play = !is_pass;
  int row = p0 < 0 ? 0 : (p0 > HH - 1 ? HH - 1 : p0);
  int col = p1 < 0 ? 0 : (p1 > WW - 1 ? WW - 1 : p1);
  int fp = row * WW + col;
  int cp = cur[b];
  int opp = 1 - cp;
  int cgbase = (b * HW + fp) * 4;
  int nr0 = cap_groups[cgbase + 0];
  int nr1 = cap_groups[cgbase + 1];
  int nr2 = cap_groups[cgbase + 2];
  int nr3 = cap_groups[cgbase + 3];

  for (int p = t; p < HW; p += blockDim.x) {
    float v = board[b * HW + p];
    float placed = (play && p == fp) ? (float)cp : v;
    int r = roots[b * HW + p];
    bool eq = (nr0 >= 0 && r == nr0) || (nr1 >= 0 && r == nr1) ||
              (nr2 >= 0 && r == nr2) || (nr3 >= 0 && r == nr3);
    bool cap = eq && (colour[b * HW + p] == opp) && play;
    out[OFF_BOARD + b * HW + p] = cap ? -1.0f : placed;
  }

  if (t == 0) {
    // ko from single-stone capture
    int tc = total_caps[b * HW + fp];
    bool single_cap = (tc == 1) && play;
    int s0 = cap_sizes[cgbase + 0];
    int s1 = cap_sizes[cgbase + 1];
    int s2 = cap_sizes[cgbase + 2];
    int s3 = cap_sizes[cgbase + 3];
    // argmax of (sizes==1): first index where true, else 0
    int dir = (s0 == 1) ? 0 : ((s1 == 1) ? 1 : ((s2 == 1) ? 2 : ((s3 == 1) ? 3 : 0)));
    const int offs[4] = {-WW, WW, -1, 1};
    int nbr = fp + offs[dir];
    // Python floor division / mod (nbr can be negative)
    int rko = (nbr >= 0) ? (nbr / WW) : -(((-nbr) + WW - 1) / WW);
    int cko = nbr - rko * WW;

    int okr, okc;
    if (is_pass) { okr = ko_pts[2 * b]; okc = ko_pts[2 * b + 1]; }
    else if (single_cap) { okr = rko; okc = cko; }
    else { okr = -1; okc = -1; }
    out[OFF_KO + 2 * b + 0] = (float)okr;
    out[OFF_KO + 2 * b + 1] = (float)okc;
    out[OFF_PASS + b] = (float)(is_pass ? pass_cnt[b] + 1 : 0);
    out[OFF_MV + b]   = (float)(mvcnt[b] + 1);
    out[OFF_PL + b]   = (float)(cp ^ 1);
  }
}

extern "C" void kernel_launch(void* const* d_in, const int* in_sizes, int n_in,
                              void* d_out, int out_size, void* d_ws, size_t ws_size,
                              hipStream_t stream) {
  const float* board      = (const float*)d_in[0];
  const int*   cur        = (const int*)d_in[1];
  const int*   ko_pts     = (const int*)d_in[2];
  const int*   pass_cnt   = (const int*)d_in[3];
  const int*   hist       = (const int*)d_in[4];
  const int*   mvcnt      = (const int*)d_in[5];
  const int*   positions  = (const int*)d_in[6];
  const int*   roots      = (const int*)d_in[7];
  const int*   colour     = (const int*)d_in[8];
  const int*   cap_groups = (const int*)d_in[9];
  const int*   cap_sizes  = (const int*)d_in[10];
  const int*   total_caps = (const int*)d_in[11];
  float* out = (float*)d_out;

  hipLaunchKernelGGL(hist_kernel, dim3(HIST_BLOCKS), dim3(256), 0, stream,
                     hist, board, mvcnt, out);
  hipLaunchKernelGGL(small_kernel, dim3(BB), dim3(128), 0, stream,
                     board, cur, ko_pts, pass_cnt, mvcnt, positions, roots,
                     colour, cap_groups, cap_sizes, total_caps, out);
}

// Round 4
// 2046.077 us; speedup vs baseline: 1.5424x; 1.0324x over previous
//
#include <hip/hip_runtime.h>

// Problem constants (Go 19x19, B=256, history_factor=10)
#define BB 256
#define HH 19
#define WW 19
#define HW 361            // H*W
#define MAXM 3610         // MAX_MOVES

constexpr unsigned PERB = (unsigned)MAXM * (unsigned)HW;   // 1,303,210 elems per batch
constexpr unsigned TOT  = (unsigned)BB * PERB;             // 333,621,760
constexpr unsigned N4   = TOT / 4u;                        // 83,405,440 vec4s
// Output layout (floats, concatenated in reference return order)
constexpr unsigned OFF_BOARD = 0;                          // B*HW
constexpr unsigned OFF_HIST  = (unsigned)BB * HW;          // 92,416 (16B aligned)
constexpr unsigned OFF_KO    = OFF_HIST + TOT;             // B*2
constexpr unsigned OFF_PASS  = OFF_KO + 2u * BB;           // B
constexpr unsigned OFF_MV    = OFF_PASS + (unsigned)BB;    // B
constexpr unsigned OFF_PL    = OFF_MV + (unsigned)BB;      // B

constexpr unsigned HIST_BLOCKS = (N4 + 255u) / 256u;       // 325,803
constexpr unsigned GRID = HIST_BLOCKS + (unsigned)BB;      // small blocks first

typedef int   vi4 __attribute__((ext_vector_type(4)));
typedef float vf4 __attribute__((ext_vector_type(4)));

__device__ __forceinline__ float state_of(float v) {
  // where(v==0, 0, where(v==1, 1, -1))
  return (v == 0.0f) ? 0.0f : ((v == 1.0f) ? 1.0f : -1.0f);
}

// Fused kernel.
// Blocks [0, BB): per-batch board update, capture, ko, scalars.
// Blocks [BB, GRID): history copy int32->float32, one vec4 per thread,
//   fully coalesced (lane i at byte 16*i), plain loads/stores — the measured
//   optimum pattern for streaming copy on MI355X (round-1 evidence; 4x-MLP
//   and nontemporal variants both regressed).
__global__ void __launch_bounds__(256) fused_kernel(
    const int* __restrict__ hist, const float* __restrict__ board,
    const int* __restrict__ move_count,
    const int* __restrict__ cur, const int* __restrict__ ko_pts,
    const int* __restrict__ pass_cnt, const int* __restrict__ positions,
    const int* __restrict__ roots, const int* __restrict__ colour,
    const int* __restrict__ cap_groups, const int* __restrict__ cap_sizes,
    const int* __restrict__ total_caps, float* __restrict__ out)
{
  if (blockIdx.x >= (unsigned)BB) {
    // ---- history copy ----
    unsigned i4 = (blockIdx.x - (unsigned)BB) * 256u + threadIdx.x;
    if (i4 >= N4) return;
    unsigned e = i4 * 4u;
    unsigned b = e / PERB;               // constant divisor -> magic mul
    unsigned j = e - b * PERB;
    vi4 h = reinterpret_cast<const vi4*>(hist)[i4];
    int mv = move_count[b];
    bool valid = (mv < MAXM);
    int mvc = mv < 0 ? 0 : (mv >= MAXM ? MAXM - 1 : mv);
    unsigned start = (unsigned)mvc * (unsigned)HW;
    vf4 o;
    if (j + 3u < PERB) {
      bool overlap = valid && (j < start + (unsigned)HW) && (j + 4u > start);
      if (!overlap) {
        // pure convert-copy (~99.99% of vec4s)
        o = __builtin_convertvector(h, vf4);
      } else {
        const float* brd = board + (size_t)b * HW;
        unsigned d;
        d = j + 0u - start; o.x = (d < (unsigned)HW) ? state_of(brd[d]) : (float)h.x;
        d = j + 1u - start; o.y = (d < (unsigned)HW) ? state_of(brd[d]) : (float)h.y;
        d = j + 2u - start; o.z = (d < (unsigned)HW) ? state_of(brd[d]) : (float)h.z;
        d = j + 3u - start; o.w = (d < (unsigned)HW) ? state_of(brd[d]) : (float)h.w;
      }
    } else {
      // batch-boundary vec4 (per-batch size % 4 == 2): per-element, rare
      float vals[4];
      int hv[4] = {h.x, h.y, h.z, h.w};
#pragma unroll
      for (int q = 0; q < 4; ++q) {
        unsigned ee = e + (unsigned)q;
        unsigned bb2 = ee / PERB;
        unsigned jj = ee - bb2 * PERB;
        int mv2 = move_count[bb2];
        int mvc2 = mv2 < 0 ? 0 : (mv2 >= MAXM ? MAXM - 1 : mv2);
        unsigned st2 = (unsigned)mvc2 * (unsigned)HW;
        bool val2 = (mv2 < MAXM);
        unsigned d = jj - st2;
        vals[q] = (val2 && d < (unsigned)HW) ? state_of(board[(size_t)bb2 * HW + d])
                                             : (float)hv[q];
      }
      o.x = vals[0]; o.y = vals[1]; o.z = vals[2]; o.w = vals[3];
    }
    reinterpret_cast<vf4*>(out + OFF_HIST)[i4] = o;
    return;
  }

  // ---- per-batch board / ko / scalars ----
  int b = blockIdx.x;
  int t = threadIdx.x;

  int p0 = positions[2 * b], p1 = positions[2 * b + 1];
  bool is_pass = (p0 < 0) || (p1 < 0);
  bool play = !is_pass;
  int row = p0 < 0 ? 0 : (p0 > HH - 1 ? HH - 1 : p0);
  int col = p1 < 0 ? 0 : (p1 > WW - 1 ? WW - 1 : p1);
  int fp = row * WW + col;
  int cp = cur[b];
  int opp = 1 - cp;
  int cgbase = (b * HW + fp) * 4;
  int nr0 = cap_groups[cgbase + 0];
  int nr1 = cap_groups[cgbase + 1];
  int nr2 = cap_groups[cgbase + 2];
  int nr3 = cap_groups[cgbase + 3];

  for (int p = t; p < HW; p += 256) {
    float v = board[b * HW + p];
    float placed = (play && p == fp) ? (float)cp : v;
    int r = roots[b * HW + p];
    bool eq = (nr0 >= 0 && r == nr0) || (nr1 >= 0 && r == nr1) ||
              (nr2 >= 0 && r == nr2) || (nr3 >= 0 && r == nr3);
    bool cap = eq && (colour[b * HW + p] == opp) && play;
    out[OFF_BOARD + b * HW + p] = cap ? -1.0f : placed;
  }

  if (t == 0) {
    // ko from single-stone capture
    int tc = total_caps[b * HW + fp];
    bool single_cap = (tc == 1) && play;
    int s0 = cap_sizes[cgbase + 0];
    int s1 = cap_sizes[cgbase + 1];
    int s2 = cap_sizes[cgbase + 2];
    int s3 = cap_sizes[cgbase + 3];
    // argmax of (sizes==1): first index where true, else 0
    int dir = (s0 == 1) ? 0 : ((s1 == 1) ? 1 : ((s2 == 1) ? 2 : ((s3 == 1) ? 3 : 0)));
    const int offs[4] = {-WW, WW, -1, 1};
    int nbr = fp + offs[dir];
    // Python floor division / mod (nbr can be negative)
    int rko = (nbr >= 0) ? (nbr / WW) : -(((-nbr) + WW - 1) / WW);
    int cko = nbr - rko * WW;

    int okr, okc;
    if (is_pass) { okr = ko_pts[2 * b]; okc = ko_pts[2 * b + 1]; }
    else if (single_cap) { okr = rko; okc = cko; }
    else { okr = -1; okc = -1; }
    out[OFF_KO + 2 * b + 0] = (float)okr;
    out[OFF_KO + 2 * b + 1] = (float)okc;
    out[OFF_PASS + b] = (float)(is_pass ? pass_cnt[b] + 1 : 0);
    out[OFF_MV + b]   = (float)(move_count[b] + 1);
    out[OFF_PL + b]   = (float)(cp ^ 1);
  }
}

extern "C" void kernel_launch(void* const* d_in, const int* in_sizes, int n_in,
                              void* d_out, int out_size, void* d_ws, size_t ws_size,
                              hipStream_t stream) {
  const float* board      = (const float*)d_in[0];
  const int*   cur        = (const int*)d_in[1];
  const int*   ko_pts     = (const int*)d_in[2];
  const int*   pass_cnt   = (const int*)d_in[3];
  const int*   hist       = (const int*)d_in[4];
  const int*   mvcnt      = (const int*)d_in[5];
  const int*   positions  = (const int*)d_in[6];
  const int*   roots      = (const int*)d_in[7];
  const int*   colour     = (const int*)d_in[8];
  const int*   cap_groups = (const int*)d_in[9];
  const int*   cap_sizes  = (const int*)d_in[10];
  const int*   total_caps = (const int*)d_in[11];
  float* out = (float*)d_out;

  hipLaunchKernelGGL(fused_kernel, dim3(GRID), dim3(256), 0, stream,
                     hist, board, mvcnt, cur, ko_pts, pass_cnt, positions,
                     roots, colour, cap_groups, cap_sizes, total_caps, out);
}